// Round 2
// baseline (42171.860 us; speedup 1.0000x reference)
//
#include <hip/hip_runtime.h>

#define BATCH 4
#define HH 256
#define WW 256
#define HT 513   // convT output spatial
#define HO 511   // final output spatial

// ---------- bf16 helpers (for h4 compact storage only) ----------
__device__ __forceinline__ float bflo(unsigned u) { return __uint_as_float(u << 16); }
__device__ __forceinline__ float bfhi(unsigned u) { return __uint_as_float(u & 0xffff0000u); }
__device__ __forceinline__ unsigned short f2bf(float f) {
    unsigned b = __float_as_uint(f);
    unsigned r = (b + 0x7fffu + ((b >> 16) & 1u)) >> 16;  // RNE
    return (unsigned short)r;
}

// ---------- 0: zero x + mask0 (contiguous) ----------
__global__ void k_zero(float* __restrict__ p, int n4) {
    int i = blockIdx.x * blockDim.x + threadIdx.x;
    if (i < n4) ((float4*)p)[i] = make_float4(0.f, 0.f, 0.f, 0.f);
}

// ---------- 1: scatter-add features (fp32), set occupancy ----------
__global__ void k_scatter(const float* __restrict__ feat,
                          const int* __restrict__ coors,
                          float* __restrict__ x, float* __restrict__ mask0, int N) {
    int t = blockIdx.x * blockDim.x + threadIdx.x;
    int n = t >> 5, c = t & 31;
    if (n >= N) return;
    int b  = coors[n * 3 + 0];
    int y  = coors[n * 3 + 1];
    int xx = coors[n * 3 + 2];
    float f = feat[n * 32 + c];
    int pix = (b * HH + y) * WW + xx;
    atomicAdd(&x[pix * 32 + c], f);
    if (c == 0) mask0[pix] = 1.0f;
}

// ---------- 2: 3x3 dilate mask ----------
__global__ void k_mask1(const float* __restrict__ mask0, float* __restrict__ mask1, int total) {
    int t = blockIdx.x * blockDim.x + threadIdx.x;
    if (t >= total) return;
    int xx = t % WW;
    int y  = (t / WW) % HH;
    int b  = t / (WW * HH);
    float m = 0.f;
    #pragma unroll
    for (int dy = -1; dy <= 1; ++dy) {
        int iy = y + dy;
        if ((unsigned)iy >= HH) continue;
        #pragma unroll
        for (int dx = -1; dx <= 1; ++dx) {
            int ix = xx + dx;
            if ((unsigned)ix >= WW) continue;
            m = fmaxf(m, mask0[(b * HH + iy) * WW + ix]);
        }
    }
    mask1[t] = (m > 0.f) ? 1.f : 0.f;
}

// ---------- 3: conv1 32->64, SAME, *mask1, +b, relu (all fp32) ----------
__global__ __launch_bounds__(256) void k_conv1(
    const float* __restrict__ in,     // [B][256][256][32]
    const float* __restrict__ w,      // [3][3][32][64]
    const float* __restrict__ bias,   // [64]
    const float* __restrict__ mask,   // [B][256][256]
    float* __restrict__ out)          // [B][256][256][64]
{
    const int NSTRIP = WW / 32;       // 8
    int blk = blockIdx.x;
    int s = blk % NSTRIP;
    int y = (blk / NSTRIP) % HH;
    int b = blk / (NSTRIP * HH);
    int lane = threadIdx.x & 63;
    int wid  = threadIdx.x >> 6;
    int px0  = s * 32 + wid * 8;

    __shared__ float wlds[32][64];    // one (ky,kx) slice, 8 KB
    float acc[8] = {0, 0, 0, 0, 0, 0, 0, 0};

    for (int k = 0; k < 9; ++k) {
        int ky = k / 3, kx = k % 3;
        __syncthreads();
        {   // 2048 floats / 256 thr = 8 each
            const float* wk = w + k * 2048 + threadIdx.x * 8;
            float4 a0 = ((const float4*)wk)[0];
            float4 a1 = ((const float4*)wk)[1];
            float* dst = &wlds[0][0] + threadIdx.x * 8;
            ((float4*)dst)[0] = a0;
            ((float4*)dst)[1] = a1;
        }
        __syncthreads();
        int iy = y + ky - 1;
        if ((unsigned)iy >= HH) continue;  // block-uniform
        const float* inrow = in + (size_t)((b * HH + iy) * WW) * 32;
        #pragma unroll
        for (int cb = 0; cb < 8; ++cb) {   // chunks of 4 ci
            float4 pk[8];
            #pragma unroll
            for (int p = 0; p < 8; ++p) {
                int ix = px0 + p + kx - 1;
                pk[p] = ((unsigned)ix < WW) ? *(const float4*)(inrow + ix * 32 + cb * 4)
                                            : make_float4(0.f, 0.f, 0.f, 0.f);
            }
            #pragma unroll
            for (int ci = 0; ci < 4; ++ci) {
                float wv = wlds[cb * 4 + ci][lane];
                #pragma unroll
                for (int p = 0; p < 8; ++p) {
                    float f = (ci == 0) ? pk[p].x : (ci == 1) ? pk[p].y : (ci == 2) ? pk[p].z : pk[p].w;
                    acc[p] = fmaf(f, wv, acc[p]);
                }
            }
        }
    }
    float bv = bias[lane];
    #pragma unroll
    for (int p = 0; p < 8; ++p) {
        int ox = px0 + p;
        int pix = (b * HH + y) * WW + ox;
        float o = (acc[p] + bv) * mask[pix];
        out[(size_t)pix * 64 + lane] = fmaxf(o, 0.f);
    }
}

// ---------- generic 3x3 conv 64->64, fp32 in/out (conv2/conv3) ----------
template <int IN_HW, int OUT_H, int OUT_W, int PAD, bool MASKED>
__global__ __launch_bounds__(256) void k_conv64f(
    const float* __restrict__ in,     // [B][IN_HW][IN_HW][64]
    const float* __restrict__ w,      // [3][3][64][64]
    const float* __restrict__ bias,   // [64]
    const float* __restrict__ mask,   // [B][OUT_H][OUT_W] (if MASKED)
    float* __restrict__ out)          // [B][OUT_H][OUT_W][64]
{
    constexpr int NSTRIP = (OUT_W + 31) / 32;
    int blk = blockIdx.x;
    int s = blk % NSTRIP;
    int y = (blk / NSTRIP) % OUT_H;
    int b = blk / (NSTRIP * OUT_H);
    int lane = threadIdx.x & 63;
    int wid  = threadIdx.x >> 6;
    int px0  = s * 32 + wid * 8;

    __shared__ float wlds[64][64];    // one (ky,kx) slice, 16 KB
    float acc[8] = {0, 0, 0, 0, 0, 0, 0, 0};

    for (int k = 0; k < 9; ++k) {
        int ky = k / 3, kx = k % 3;
        __syncthreads();
        {   // 4096 floats / 256 thr = 16 each
            const float* wk = w + k * 4096 + threadIdx.x * 16;
            float4 a0 = ((const float4*)wk)[0];
            float4 a1 = ((const float4*)wk)[1];
            float4 a2 = ((const float4*)wk)[2];
            float4 a3 = ((const float4*)wk)[3];
            float* dst = &wlds[0][0] + threadIdx.x * 16;
            ((float4*)dst)[0] = a0;
            ((float4*)dst)[1] = a1;
            ((float4*)dst)[2] = a2;
            ((float4*)dst)[3] = a3;
        }
        __syncthreads();
        int iy = y + ky - PAD;
        if ((unsigned)iy >= IN_HW) continue;  // block-uniform
        const float* inrow = in + (size_t)((b * IN_HW + iy) * IN_HW) * 64;
        #pragma unroll
        for (int cb = 0; cb < 16; ++cb) {     // chunks of 4 ci
            float4 pk[8];
            #pragma unroll
            for (int p = 0; p < 8; ++p) {
                int ox = px0 + p;
                int ix = ox + kx - PAD;
                bool v = (ox < OUT_W) && ((unsigned)ix < IN_HW);
                pk[p] = v ? *(const float4*)(inrow + ix * 64 + cb * 4)
                          : make_float4(0.f, 0.f, 0.f, 0.f);
            }
            #pragma unroll
            for (int ci = 0; ci < 4; ++ci) {
                float wv = wlds[cb * 4 + ci][lane];
                #pragma unroll
                for (int p = 0; p < 8; ++p) {
                    float f = (ci == 0) ? pk[p].x : (ci == 1) ? pk[p].y : (ci == 2) ? pk[p].z : pk[p].w;
                    acc[p] = fmaf(f, wv, acc[p]);
                }
            }
        }
    }
    float bv = bias[lane];
    #pragma unroll
    for (int p = 0; p < 8; ++p) {
        int ox = px0 + p;
        if (ox < OUT_W) {
            int pix = (b * OUT_H + y) * OUT_W + ox;
            float m = 1.f;
            if constexpr (MASKED) m = mask[pix];
            float o = (acc[p] + bv) * m;
            out[(size_t)pix * 64 + lane] = fmaxf(o, 0.f);
        }
    }
}

// ---------- convT: stride-2 3x3 transpose conv 256->513, *mask4, +b, relu ----------
// fp32 in, bf16 out (h4 compact storage)
__global__ __launch_bounds__(256) void k_convT(
    const float* __restrict__ in,     // [B][256][256][64]
    const float* __restrict__ w,      // [3][3][64][64]
    const float* __restrict__ bias,   // [64]
    const float* __restrict__ mask1,  // [B][256][256]
    unsigned short* __restrict__ out) // [B][513][513][64] bf16
{
    const int NSTRIP = (HT + 31) / 32;  // 17
    int blk = blockIdx.x;
    int s = blk % NSTRIP;
    int y = (blk / NSTRIP) % HT;        // oy
    int b = blk / (NSTRIP * HT);
    int lane = threadIdx.x & 63;
    int wid  = threadIdx.x >> 6;
    int px0  = s * 32 + wid * 8;

    __shared__ float wlds[64][64];
    float acc[8] = {0, 0, 0, 0, 0, 0, 0, 0};
    float m4[8]  = {0, 0, 0, 0, 0, 0, 0, 0};

    for (int k = 0; k < 9; ++k) {
        int ky = k / 3, kx = k % 3;
        __syncthreads();
        {
            const float* wk = w + k * 4096 + threadIdx.x * 16;
            float4 a0 = ((const float4*)wk)[0];
            float4 a1 = ((const float4*)wk)[1];
            float4 a2 = ((const float4*)wk)[2];
            float4 a3 = ((const float4*)wk)[3];
            float* dst = &wlds[0][0] + threadIdx.x * 16;
            ((float4*)dst)[0] = a0;
            ((float4*)dst)[1] = a1;
            ((float4*)dst)[2] = a2;
            ((float4*)dst)[3] = a3;
        }
        __syncthreads();
        // dilated-conv tap: input row iy participates iff (oy+ky-2) even & in range
        int q = y + ky - 2;
        if ((q & 1) || ((unsigned)(q >> 1) >= 256u)) continue;  // block-uniform
        int iy = q >> 1;
        const float* inrow = in + (size_t)((b * HH + iy) * WW) * 64;
        const float* mrow  = mask1 + (b * HH + iy) * WW;

        bool pv[8];
        int  ixs[8];
        #pragma unroll
        for (int p = 0; p < 8; ++p) {
            int ox = px0 + p;
            int r = ox + kx - 2;
            pv[p]  = (ox < HT) && !(r & 1) && ((unsigned)(r >> 1) < 256u);
            ixs[p] = r >> 1;
            if (pv[p]) m4[p] = fmaxf(m4[p], mrow[ixs[p]]);
        }
        #pragma unroll
        for (int cb = 0; cb < 16; ++cb) {
            float4 pk[8];
            #pragma unroll
            for (int p = 0; p < 8; ++p) {
                pk[p] = pv[p] ? *(const float4*)(inrow + ixs[p] * 64 + cb * 4)
                              : make_float4(0.f, 0.f, 0.f, 0.f);
            }
            #pragma unroll
            for (int ci = 0; ci < 4; ++ci) {
                float wv = wlds[cb * 4 + ci][lane];
                #pragma unroll
                for (int p = 0; p < 8; ++p) {
                    float f = (ci == 0) ? pk[p].x : (ci == 1) ? pk[p].y : (ci == 2) ? pk[p].z : pk[p].w;
                    acc[p] = fmaf(f, wv, acc[p]);
                }
            }
        }
    }
    float bv = bias[lane];
    #pragma unroll
    for (int p = 0; p < 8; ++p) {
        int ox = px0 + p;
        if (ox < HT) {
            float mm = (m4[p] > 0.f) ? 1.f : 0.f;
            float o = (acc[p] + bv) * mm;
            o = fmaxf(o, 0.f);
            out[(size_t)((b * HT + y) * HT + ox) * 64 + lane] = f2bf(o);
        }
    }
}

// ---------- conv5: 3x3 VALID 64->64, bf16 in, fp32 out, +b, relu ----------
__global__ __launch_bounds__(256) void k_conv5(
    const unsigned short* __restrict__ in,  // [B][513][513][64] bf16
    const float* __restrict__ w,            // [3][3][64][64]
    const float* __restrict__ bias,         // [64]
    float* __restrict__ out)                // [B][511][511][64]
{
    const int NSTRIP = (HO + 31) / 32;      // 16
    int blk = blockIdx.x;
    int s = blk % NSTRIP;
    int y = (blk / NSTRIP) % HO;
    int b = blk / (NSTRIP * HO);
    int lane = threadIdx.x & 63;
    int wid  = threadIdx.x >> 6;
    int px0  = s * 32 + wid * 8;

    __shared__ float wlds[64][64];
    float acc[8] = {0, 0, 0, 0, 0, 0, 0, 0};

    for (int k = 0; k < 9; ++k) {
        int ky = k / 3, kx = k % 3;
        __syncthreads();
        {
            const float* wk = w + k * 4096 + threadIdx.x * 16;
            float4 a0 = ((const float4*)wk)[0];
            float4 a1 = ((const float4*)wk)[1];
            float4 a2 = ((const float4*)wk)[2];
            float4 a3 = ((const float4*)wk)[3];
            float* dst = &wlds[0][0] + threadIdx.x * 16;
            ((float4*)dst)[0] = a0;
            ((float4*)dst)[1] = a1;
            ((float4*)dst)[2] = a2;
            ((float4*)dst)[3] = a3;
        }
        __syncthreads();
        int iy = y + ky;                     // VALID: iy in [0,513)
        const unsigned short* inrow = in + (size_t)((b * HT + iy) * HT) * 64;
        #pragma unroll
        for (int cb = 0; cb < 8; ++cb) {     // chunks of 8 ci (uint4 = 8 bf16)
            uint4 pk[8];
            #pragma unroll
            for (int p = 0; p < 8; ++p) {
                int ox = px0 + p;
                int ix = ox + kx;            // [0,513)
                bool v = (ox < HO);
                pk[p] = v ? *(const uint4*)(inrow + ix * 64 + cb * 8)
                          : make_uint4(0u, 0u, 0u, 0u);
            }
            #pragma unroll
            for (int ci = 0; ci < 8; ++ci) {
                float wv = wlds[cb * 8 + ci][lane];
                const int h = ci >> 1;
                #pragma unroll
                for (int p = 0; p < 8; ++p) {
                    unsigned u = (h == 0) ? pk[p].x : (h == 1) ? pk[p].y : (h == 2) ? pk[p].z : pk[p].w;
                    float f = (ci & 1) ? bfhi(u) : bflo(u);
                    acc[p] = fmaf(f, wv, acc[p]);
                }
            }
        }
    }
    float bv = bias[lane];
    #pragma unroll
    for (int p = 0; p < 8; ++p) {
        int ox = px0 + p;
        if (ox < HO) {
            int pix = (b * HO + y) * HO + ox;
            out[(size_t)pix * 64 + lane] = fmaxf(acc[p] + bv, 0.f);
        }
    }
}

// ---------- host ----------
extern "C" void kernel_launch(void* const* d_in, const int* in_sizes, int n_in,
                              void* d_out, int out_size, void* d_ws, size_t ws_size,
                              hipStream_t stream) {
    const float* feat = (const float*)d_in[0];
    const int* coors  = (const int*)d_in[1];
    const float* w1 = (const float*)d_in[3];
    const float* b1 = (const float*)d_in[4];
    const float* w2 = (const float*)d_in[5];
    const float* b2 = (const float*)d_in[6];
    const float* w3 = (const float*)d_in[7];
    const float* b3 = (const float*)d_in[8];
    const float* wt = (const float*)d_in[9];
    const float* bt = (const float*)d_in[10];
    const float* w5 = (const float*)d_in[11];
    const float* b5 = (const float*)d_in[12];

    int N = in_sizes[0] / 32;  // 200000

    // Workspace layout (~203 MB total), with region R reused over time:
    //   [h1 fp32 64MB][mask1 fp32 1MB][R 134.7MB]
    //   R holds: x(33.5MB)+mask0(1MB)  ->  h2 fp32(64MB)  ->  h4 bf16(134.7MB)
    char* ws = (char*)d_ws;
    float* h1    = (float*)ws;                         // 67,108,864 B
    float* mask1 = (float*)(ws + 67108864);            //  1,048,576 B
    char*  R     = ws + 68157440;
    float* x     = (float*)R;                          // 33,554,432 B
    float* mask0 = (float*)(R + 33554432);             //  1,048,576 B
    float* h2    = (float*)R;                          // 67,108,864 B (reuses x/mask0)
    unsigned short* h4 = (unsigned short*)R;           // 134,742,528 B (reuses h2)

    // 0: zero x + mask0 (contiguous)
    int nz4 = (8388608 + 262144) / 4;
    k_zero<<<(nz4 + 255) / 256, 256, 0, stream>>>(x, nz4);

    // 1: scatter
    k_scatter<<<(N * 32 + 255) / 256, 256, 0, stream>>>(feat, coors, x, mask0, N);

    // 2: mask dilation
    k_mask1<<<(BATCH * HH * WW) / 256, 256, 0, stream>>>(mask0, mask1, BATCH * HH * WW);

    // 3-5: conv stack at 256x256
    k_conv1<<<BATCH * HH * (WW / 32), 256, 0, stream>>>(x, w1, b1, mask1, h1);
    k_conv64f<256, 256, 256, 1, true><<<BATCH * HH * (WW / 32), 256, 0, stream>>>(h1, w2, b2, mask1, h2);
    k_conv64f<256, 256, 256, 1, true><<<BATCH * HH * (WW / 32), 256, 0, stream>>>(h2, w3, b3, mask1, h1);

    // 6: transpose conv 256 -> 513 (mask4 computed inline), bf16 out
    k_convT<<<BATCH * HT * ((HT + 31) / 32), 256, 0, stream>>>(h1, wt, bt, mask1, h4);

    // 7: final VALID conv 513 -> 511 into d_out (fp32)
    k_conv5<<<BATCH * HO * ((HO + 31) / 32), 256, 0, stream>>>(h4, w5, b5, (float*)d_out);
}

// Round 3
// 903.584 us; speedup vs baseline: 46.6718x; 46.6718x over previous
//
#include <hip/hip_runtime.h>

#define BATCH 4
#define HH 256
#define WW 256
#define HT 513   // convT output spatial
#define HO 511   // final output spatial

typedef __attribute__((ext_vector_type(8))) short bf16x8;
typedef __attribute__((ext_vector_type(4))) float f32x4;

// ---------- bf16 helpers ----------
__device__ __forceinline__ unsigned short f2bf(float f) {
    unsigned b = __float_as_uint(f);
    unsigned r = (b + 0x7fffu + ((b >> 16) & 1u)) >> 16;  // RNE
    return (unsigned short)r;
}

// ---------- 0: zero mask0 + x (contiguous region) ----------
__global__ void k_zero(float* __restrict__ p, int n4) {
    int i = blockIdx.x * blockDim.x + threadIdx.x;
    if (i < n4) ((float4*)p)[i] = make_float4(0.f, 0.f, 0.f, 0.f);
}

// ---------- 1: scatter-add features (fp32), set occupancy ----------
__global__ void k_scatter(const float* __restrict__ feat,
                          const int* __restrict__ coors,
                          float* __restrict__ x, float* __restrict__ mask0, int N) {
    int t = blockIdx.x * blockDim.x + threadIdx.x;
    int n = t >> 5, c = t & 31;
    if (n >= N) return;
    int b  = coors[n * 3 + 0];
    int y  = coors[n * 3 + 1];
    int xx = coors[n * 3 + 2];
    float f = feat[n * 32 + c];
    int pix = (b * HH + y) * WW + xx;
    atomicAdd(&x[pix * 32 + c], f);
    if (c == 0) mask0[pix] = 1.0f;
}

// ---------- 2: 3x3 dilate mask (SAME) ----------
__global__ void k_mask1(const float* __restrict__ mask0, float* __restrict__ mask1, int total) {
    int t = blockIdx.x * blockDim.x + threadIdx.x;
    if (t >= total) return;
    int xx = t % WW;
    int y  = (t / WW) % HH;
    int b  = t / (WW * HH);
    float m = 0.f;
    #pragma unroll
    for (int dy = -1; dy <= 1; ++dy) {
        int iy = y + dy;
        if ((unsigned)iy >= HH) continue;
        #pragma unroll
        for (int dx = -1; dx <= 1; ++dx) {
            int ix = xx + dx;
            if ((unsigned)ix >= WW) continue;
            m = fmaxf(m, mask0[(b * HH + iy) * WW + ix]);
        }
    }
    mask1[t] = (m > 0.f) ? 1.f : 0.f;
}

// ---------- 2b: transpose-dilate mask: mask4[B][513][513] ----------
__global__ void k_mask4(const float* __restrict__ mask1, float* __restrict__ mask4, int total) {
    int t = blockIdx.x * blockDim.x + threadIdx.x;
    if (t >= total) return;
    int ox = t % HT;
    int oy = (t / HT) % HT;
    int b  = t / (HT * HT);
    float m = 0.f;
    #pragma unroll
    for (int ky = 0; ky < 3; ++ky) {
        int q = oy + ky - 2;
        if ((q & 1) || (unsigned)(q >> 1) >= (unsigned)HH) continue;
        int iy = q >> 1;
        #pragma unroll
        for (int kx = 0; kx < 3; ++kx) {
            int r = ox + kx - 2;
            if ((r & 1) || (unsigned)(r >> 1) >= (unsigned)WW) continue;
            m = fmaxf(m, mask1[(b * HH + iy) * WW + (r >> 1)]);
        }
    }
    mask4[t] = (m > 0.f) ? 1.f : 0.f;
}

// ---------- 2c: cast x fp32 -> bf16 (8 elems/thread) ----------
__global__ void k_cast(const float* __restrict__ src, unsigned short* __restrict__ dst, int n8) {
    int i = blockIdx.x * blockDim.x + threadIdx.x;
    if (i >= n8) return;
    float4 a = ((const float4*)src)[2 * i];
    float4 c = ((const float4*)src)[2 * i + 1];
    uint4 o;
    o.x = (unsigned)f2bf(a.x) | ((unsigned)f2bf(a.y) << 16);
    o.y = (unsigned)f2bf(a.z) | ((unsigned)f2bf(a.w) << 16);
    o.z = (unsigned)f2bf(c.x) | ((unsigned)f2bf(c.y) << 16);
    o.w = (unsigned)f2bf(c.z) | ((unsigned)f2bf(c.w) << 16);
    ((uint4*)dst)[i] = o;
}

// ---------- 2d: pack weights [K][64] fp32 -> MFMA B-fragment order ----------
// dst[t][nb][lane][j] (bf16) = w[k][n], k = t*32 + (lane>>4)*8 + j, n = nb*16 + (lane&15)
__global__ void k_pack(const float* __restrict__ w, unsigned short* __restrict__ dst, int T) {
    int t = blockIdx.x * blockDim.x + threadIdx.x;
    if (t >= T * 256) return;
    int step = t >> 8;
    int r = t & 255;
    int nb = r >> 6;
    int l = r & 63;
    int k = step * 32 + ((l >> 4) * 8);
    int n = nb * 16 + (l & 15);
    unsigned short tmp[8];
    #pragma unroll
    for (int j = 0; j < 8; ++j) tmp[j] = f2bf(w[(size_t)(k + j) * 64 + n]);
    uint4 o;
    o.x = (unsigned)tmp[0] | ((unsigned)tmp[1] << 16);
    o.y = (unsigned)tmp[2] | ((unsigned)tmp[3] << 16);
    o.z = (unsigned)tmp[4] | ((unsigned)tmp[5] << 16);
    o.w = (unsigned)tmp[6] | ((unsigned)tmp[7] << 16);
    *(uint4*)(dst + (size_t)((step * 4 + nb) * 64 + l) * 8) = o;
}

// ---------- generic MFMA conv: M=pixels, N=64 cout, K=T*32 ----------
enum Mode { CONV, CONVT };

template <int CIN, int T, int IN_H, int IN_W, int OUT_H, int OUT_W, int PAD,
          Mode MODE, bool MASKED, bool OUT_F32>
__global__ __launch_bounds__(256) void k_conv_mfma(
    const unsigned short* __restrict__ in,   // bf16 [B][IN_H][IN_W][CIN]
    const unsigned short* __restrict__ bp,   // packed B frags [T][4][64][8]
    const float* __restrict__ bias,          // [64]
    const float* __restrict__ mask,          // [B][OUT_H][OUT_W] (if MASKED)
    void* __restrict__ outv)                 // bf16 or fp32 [B][OUT_H][OUT_W][64]
{
    constexpr int XT = (OUT_W + 63) / 64;
    int blk = blockIdx.x;
    int s = blk % XT;
    int y = (blk / XT) % OUT_H;
    int b = blk / (XT * OUT_H);
    int lane = threadIdx.x & 63;
    int wid  = threadIdx.x >> 6;
    int m    = lane & 15;
    int quad = lane >> 4;
    int px0  = s * 64 + wid * 16;
    int ox   = px0 + m;

    f32x4 acc0 = {0.f, 0.f, 0.f, 0.f};
    f32x4 acc1 = {0.f, 0.f, 0.f, 0.f};
    f32x4 acc2 = {0.f, 0.f, 0.f, 0.f};
    f32x4 acc3 = {0.f, 0.f, 0.f, 0.f};

    #pragma unroll
    for (int t = 0; t < T; ++t) {
        constexpr int TPC = (CIN == 64) ? 2 : 1;   // K-steps per tap
        int tap = t / TPC;
        int ci0 = (t % TPC) * 32;
        int ky = tap / 3, kx = tap % 3;
        int iy, ix;
        bool rowv, v;
        if constexpr (MODE == CONV) {
            iy = y + ky - PAD;
            rowv = (unsigned)iy < (unsigned)IN_H;
            ix = ox + kx - PAD;
            v = (ox < OUT_W) & ((unsigned)ix < (unsigned)IN_W);
        } else {
            int q = y + ky - 2;
            rowv = (!(q & 1)) && ((unsigned)(q >> 1) < (unsigned)IN_H);
            iy = q >> 1;
            int r = ox + kx - 2;
            v = (ox < OUT_W) & (!(r & 1)) & ((unsigned)(r >> 1) < (unsigned)IN_W);
            ix = r >> 1;
        }
        if (!rowv) continue;                       // wave-uniform
        int ixc = min(max(ix, 0), IN_W - 1);
        const unsigned short* ap =
            in + ((size_t)(b * IN_H + iy) * IN_W + ixc) * CIN + ci0 + quad * 8;
        uint4 av = v ? *(const uint4*)ap : make_uint4(0u, 0u, 0u, 0u);
        bf16x8 a = __builtin_bit_cast(bf16x8, av);
        const unsigned short* bpt = bp + (size_t)t * 2048 + lane * 8;  // nb stride 512
        bf16x8 b0 = *(const bf16x8*)(bpt);
        bf16x8 b1 = *(const bf16x8*)(bpt + 512);
        bf16x8 b2 = *(const bf16x8*)(bpt + 1024);
        bf16x8 b3 = *(const bf16x8*)(bpt + 1536);
        acc0 = __builtin_amdgcn_mfma_f32_16x16x32_bf16(a, b0, acc0, 0, 0, 0);
        acc1 = __builtin_amdgcn_mfma_f32_16x16x32_bf16(a, b1, acc1, 0, 0, 0);
        acc2 = __builtin_amdgcn_mfma_f32_16x16x32_bf16(a, b2, acc2, 0, 0, 0);
        acc3 = __builtin_amdgcn_mfma_f32_16x16x32_bf16(a, b3, acc3, 0, 0, 0);
    }

    // epilogue: C/D layout col = lane&15 (cout within nb), row = quad*4+reg (pixel)
    int n0 = lane & 15;
    float bv0 = bias[n0], bv1 = bias[16 + n0], bv2 = bias[32 + n0], bv3 = bias[48 + n0];
    #pragma unroll
    for (int reg = 0; reg < 4; ++reg) {
        int pm = px0 + quad * 4 + reg;
        if (pm >= OUT_W) continue;
        size_t pix = (size_t)(b * OUT_H + y) * OUT_W + pm;
        float mk = 1.f;
        if constexpr (MASKED) mk = mask[pix];
        float o0 = fmaxf((acc0[reg] + bv0) * mk, 0.f);
        float o1 = fmaxf((acc1[reg] + bv1) * mk, 0.f);
        float o2 = fmaxf((acc2[reg] + bv2) * mk, 0.f);
        float o3 = fmaxf((acc3[reg] + bv3) * mk, 0.f);
        if constexpr (OUT_F32) {
            float* op = (float*)outv + pix * 64 + n0;
            op[0] = o0; op[16] = o1; op[32] = o2; op[48] = o3;
        } else {
            unsigned short* op = (unsigned short*)outv + pix * 64 + n0;
            op[0] = f2bf(o0); op[16] = f2bf(o1); op[32] = f2bf(o2); op[48] = f2bf(o3);
        }
    }
}

// ---------- host ----------
extern "C" void kernel_launch(void* const* d_in, const int* in_sizes, int n_in,
                              void* d_out, int out_size, void* d_ws, size_t ws_size,
                              hipStream_t stream) {
    const float* feat = (const float*)d_in[0];
    const int* coors  = (const int*)d_in[1];
    const float* w1 = (const float*)d_in[3];
    const float* b1 = (const float*)d_in[4];
    const float* w2 = (const float*)d_in[5];
    const float* b2 = (const float*)d_in[6];
    const float* w3 = (const float*)d_in[7];
    const float* b3 = (const float*)d_in[8];
    const float* wt = (const float*)d_in[9];
    const float* bt = (const float*)d_in[10];
    const float* w5 = (const float*)d_in[11];
    const float* b5 = (const float*)d_in[12];

    int N = in_sizes[0] / 32;  // 200000

    const size_t MB = 1024 * 1024;
    char* ws = (char*)d_ws;
    // layout (liveness-based reuse), total 177 MB:
    unsigned short* pk1 = (unsigned short*)(ws);             // 36,864 B
    unsigned short* pk2 = (unsigned short*)(ws + 36864);     // 73,728 B
    unsigned short* pk3 = (unsigned short*)(ws + 110592);
    unsigned short* pkt = (unsigned short*)(ws + 184320);
    unsigned short* pk5 = (unsigned short*)(ws + 258048);    // ends 331,776
    float* mask1 = (float*)(ws + 1 * MB);                    // 1 MB
    float* mask4 = (float*)(ws + 2 * MB);                    // 4.02 MB
    float* mask0 = (float*)(ws + 7 * MB);                    // 1 MB   (contiguous with x)
    float* x_f32 = (float*)(ws + 8 * MB);                    // 33.55 MB
    unsigned short* x_bf  = (unsigned short*)(ws + 42 * MB); // 16.78 MB
    unsigned short* h1    = (unsigned short*)(ws + 59 * MB); // 33.55 MB
    unsigned short* h2    = (unsigned short*)(ws + 93 * MB); // 33.55 MB
    unsigned short* h3    = (unsigned short*)(ws + 8 * MB);  // reuses x_f32 (dead after cast)
    unsigned short* h4    = (unsigned short*)(ws + 42 * MB); // 134.75 MB, reuses x_bf/h1/h2

    // 0: zero mask0 + x (contiguous 34,603,008 B)
    int nz4 = (262144 + 8388608) / 4;
    k_zero<<<(nz4 + 255) / 256, 256, 0, stream>>>(mask0, nz4);

    // 1: scatter (fp32 atomics)
    k_scatter<<<(N * 32 + 255) / 256, 256, 0, stream>>>(feat, coors, x_f32, mask0, N);

    // 2: masks + cast + weight packing
    k_mask1<<<(BATCH * HH * WW) / 256, 256, 0, stream>>>(mask0, mask1, BATCH * HH * WW);
    int m4tot = BATCH * HT * HT;
    k_mask4<<<(m4tot + 255) / 256, 256, 0, stream>>>(mask1, mask4, m4tot);
    k_cast<<<(1048576 + 255) / 256, 256, 0, stream>>>(x_f32, x_bf, 1048576);
    k_pack<<<9, 256, 0, stream>>>(w1, pk1, 9);
    k_pack<<<18, 256, 0, stream>>>(w2, pk2, 18);
    k_pack<<<18, 256, 0, stream>>>(w3, pk3, 18);
    k_pack<<<18, 256, 0, stream>>>(wt, pkt, 18);
    k_pack<<<18, 256, 0, stream>>>(w5, pk5, 18);

    // 3-5: conv stack at 256x256 (bf16 MFMA)
    k_conv_mfma<32, 9, 256, 256, 256, 256, 1, CONV, true, false>
        <<<BATCH * HH * 4, 256, 0, stream>>>(x_bf, pk1, b1, mask1, h1);
    k_conv_mfma<64, 18, 256, 256, 256, 256, 1, CONV, true, false>
        <<<BATCH * HH * 4, 256, 0, stream>>>(h1, pk2, b2, mask1, h2);
    k_conv_mfma<64, 18, 256, 256, 256, 256, 1, CONV, true, false>
        <<<BATCH * HH * 4, 256, 0, stream>>>(h2, pk3, b3, mask1, h3);

    // 6: transpose conv 256 -> 513 (parity-aware gather)
    k_conv_mfma<64, 18, 256, 256, HT, HT, 0, CONVT, true, false>
        <<<BATCH * HT * 9, 256, 0, stream>>>(h3, pkt, bt, mask4, h4);

    // 7: final VALID conv 513 -> 511 into d_out (fp32)
    k_conv_mfma<64, 18, HT, HT, HO, HO, 0, CONV, false, true>
        <<<BATCH * HO * 8, 256, 0, stream>>>(h4, pk5, b5, nullptr, (float*)d_out);
}

// Round 4
// 787.055 us; speedup vs baseline: 53.5819x; 1.1481x over previous
//
#include <hip/hip_runtime.h>

#define BATCH 4
#define HH 256
#define WW 256
#define HT 513   // convT output spatial
#define HO 511   // final output spatial

typedef __attribute__((ext_vector_type(8))) short bf16x8;
typedef __attribute__((ext_vector_type(4))) float f32x4;

// ---------- bf16 helpers ----------
__device__ __forceinline__ unsigned short f2bf(float f) {
    unsigned b = __float_as_uint(f);
    unsigned r = (b + 0x7fffu + ((b >> 16) & 1u)) >> 16;  // RNE
    return (unsigned short)r;
}

// ---------- 0: zero mask0 + x (contiguous region) ----------
__global__ void k_zero(float* __restrict__ p, int n4) {
    int i = blockIdx.x * blockDim.x + threadIdx.x;
    if (i < n4) ((float4*)p)[i] = make_float4(0.f, 0.f, 0.f, 0.f);
}

// ---------- 1: scatter-add features (fp32), set occupancy ----------
__global__ void k_scatter(const float* __restrict__ feat,
                          const int* __restrict__ coors,
                          float* __restrict__ x, float* __restrict__ mask0, int N) {
    int t = blockIdx.x * blockDim.x + threadIdx.x;
    int n = t >> 5, c = t & 31;
    if (n >= N) return;
    int b  = coors[n * 3 + 0];
    int y  = coors[n * 3 + 1];
    int xx = coors[n * 3 + 2];
    float f = feat[n * 32 + c];
    int pix = (b * HH + y) * WW + xx;
    atomicAdd(&x[pix * 32 + c], f);
    if (c == 0) mask0[pix] = 1.0f;
}

// ---------- 2: 3x3 dilate mask (SAME) ----------
__global__ void k_mask1(const float* __restrict__ mask0, float* __restrict__ mask1, int total) {
    int t = blockIdx.x * blockDim.x + threadIdx.x;
    if (t >= total) return;
    int xx = t % WW;
    int y  = (t / WW) % HH;
    int b  = t / (WW * HH);
    float m = 0.f;
    #pragma unroll
    for (int dy = -1; dy <= 1; ++dy) {
        int iy = y + dy;
        if ((unsigned)iy >= HH) continue;
        #pragma unroll
        for (int dx = -1; dx <= 1; ++dx) {
            int ix = xx + dx;
            if ((unsigned)ix >= WW) continue;
            m = fmaxf(m, mask0[(b * HH + iy) * WW + ix]);
        }
    }
    mask1[t] = (m > 0.f) ? 1.f : 0.f;
}

// ---------- 2b: transpose-dilate mask: mask4[B][513][513] ----------
__global__ void k_mask4(const float* __restrict__ mask1, float* __restrict__ mask4, int total) {
    int t = blockIdx.x * blockDim.x + threadIdx.x;
    if (t >= total) return;
    int ox = t % HT;
    int oy = (t / HT) % HT;
    int b  = t / (HT * HT);
    float m = 0.f;
    #pragma unroll
    for (int ky = 0; ky < 3; ++ky) {
        int q = oy + ky - 2;
        if ((q & 1) || (unsigned)(q >> 1) >= (unsigned)HH) continue;
        int iy = q >> 1;
        #pragma unroll
        for (int kx = 0; kx < 3; ++kx) {
            int r = ox + kx - 2;
            if ((r & 1) || (unsigned)(r >> 1) >= (unsigned)WW) continue;
            m = fmaxf(m, mask1[(b * HH + iy) * WW + (r >> 1)]);
        }
    }
    mask4[t] = (m > 0.f) ? 1.f : 0.f;
}

// ---------- 2c: cast x fp32 -> bf16 (8 elems/thread) ----------
__global__ void k_cast(const float* __restrict__ src, unsigned short* __restrict__ dst, int n8) {
    int i = blockIdx.x * blockDim.x + threadIdx.x;
    if (i >= n8) return;
    float4 a = ((const float4*)src)[2 * i];
    float4 c = ((const float4*)src)[2 * i + 1];
    uint4 o;
    o.x = (unsigned)f2bf(a.x) | ((unsigned)f2bf(a.y) << 16);
    o.y = (unsigned)f2bf(a.z) | ((unsigned)f2bf(a.w) << 16);
    o.z = (unsigned)f2bf(c.x) | ((unsigned)f2bf(c.y) << 16);
    o.w = (unsigned)f2bf(c.z) | ((unsigned)f2bf(c.w) << 16);
    ((uint4*)dst)[i] = o;
}

// ---------- 2d: pack weights [K][64] fp32 -> MFMA B-fragment order ----------
// dst[t][nb][lane][j] (bf16) = w[k][n], k = t*32 + (lane>>4)*8 + j, n = nb*16 + (lane&15)
__global__ void k_pack(const float* __restrict__ w, unsigned short* __restrict__ dst, int T) {
    int t = blockIdx.x * blockDim.x + threadIdx.x;
    if (t >= T * 256) return;
    int step = t >> 8;
    int r = t & 255;
    int nb = r >> 6;
    int l = r & 63;
    int k = step * 32 + ((l >> 4) * 8);
    int n = nb * 16 + (l & 15);
    unsigned short tmp[8];
    #pragma unroll
    for (int j = 0; j < 8; ++j) tmp[j] = f2bf(w[(size_t)(k + j) * 64 + n]);
    uint4 o;
    o.x = (unsigned)tmp[0] | ((unsigned)tmp[1] << 16);
    o.y = (unsigned)tmp[2] | ((unsigned)tmp[3] << 16);
    o.z = (unsigned)tmp[4] | ((unsigned)tmp[5] << 16);
    o.w = (unsigned)tmp[6] | ((unsigned)tmp[7] << 16);
    *(uint4*)(dst + (size_t)((step * 4 + nb) * 64 + l) * 8) = o;
}

// ---------- MFMA conv: wave = 64 px x 64 cout, B staged in LDS per-ky phase ----------
enum Mode { CONV, CONVT2 };

template <int CIN, int IN_H, int IN_W, int OUT_H, int OUT_W, int PAD,
          Mode MODE, bool MASKED, bool OUT_F32>
__global__ __launch_bounds__(256) void k_conv_mfma(
    const unsigned short* __restrict__ in,   // bf16 [B][IN_H][IN_W][CIN]
    const unsigned short* __restrict__ bp,   // packed B frags [T][4][64][8], T=9*CIN/32
    const float* __restrict__ bias,          // [64]
    const float* __restrict__ mask,          // [B][OUT_H][OUT_W] (if MASKED)
    void* __restrict__ outv)                 // bf16 or fp32 [B][OUT_H][OUT_W][64]
{
    constexpr int H2 = CIN / 32;                 // K-steps per tap
    constexpr int XT = (OUT_W + 255) / 256;      // 256 px per block
    __shared__ __align__(16) unsigned short lb[3 * H2 * 2048];  // one ky-phase of B

    int blk = blockIdx.x;
    int s = blk % XT;
    int y = (blk / XT) % OUT_H;
    int b = blk / (XT * OUT_H);
    int tid  = threadIdx.x;
    int lane = tid & 63;
    int wid  = tid >> 6;
    int m    = lane & 15;
    int quad = lane >> 4;

    int px_base, par;
    if constexpr (MODE == CONV) { px_base = s * 256 + wid * 64; par = 0; }
    else { par = wid & 1; px_base = s * 256 + (wid >> 1) * 128; }

    f32x4 acc[4][4] = {};

    #pragma unroll
    for (int ky = 0; ky < 3; ++ky) {
        int iy; bool rowv;
        if constexpr (MODE == CONV) {
            iy = y + ky - PAD;
            rowv = (unsigned)iy < (unsigned)IN_H;
        } else {
            int q = y + ky - 2;
            rowv = (!(q & 1)) && ((unsigned)(q >> 1) < (unsigned)IN_H);
            iy = q >> 1;
        }
        if (!rowv) continue;                      // block-uniform (y, ky uniform)

        __syncthreads();
        {   // stage this ky's 3*H2 t-steps of packed B into LDS (12/24 KB)
            const uint4* src = (const uint4*)bp + (size_t)ky * 3 * H2 * 256;
            uint4* dst = (uint4*)lb;
            #pragma unroll
            for (int j = 0; j < 3 * H2; ++j)
                dst[j * 256 + tid] = src[j * 256 + tid];
        }
        __syncthreads();

        const unsigned short* inrow = in + (size_t)(b * IN_H + iy) * IN_W * CIN;

        #pragma unroll
        for (int kx = 0; kx < 3; ++kx) {
            if constexpr (MODE == CONVT2) {
                if ((kx & 1) != par) continue;    // wave-uniform parity skip
            }
            int ix[4]; bool v[4];
            #pragma unroll
            for (int f = 0; f < 4; ++f) {
                if constexpr (MODE == CONV) {
                    int ox = px_base + f * 16 + m;
                    int t = ox + kx - PAD;
                    v[f]  = (ox < OUT_W) & ((unsigned)t < (unsigned)IN_W);
                    ix[f] = min(max(t, 0), IN_W - 1);
                } else {
                    int ox = px_base + 2 * (f * 16 + m) + par;
                    int r = ox + kx - 2;          // even by construction
                    int t = r >> 1;
                    v[f]  = (ox < OUT_W) & ((unsigned)t < (unsigned)IN_W);
                    ix[f] = min(max(t, 0), IN_W - 1);
                }
            }
            #pragma unroll
            for (int half = 0; half < H2; ++half) {
                int tl = kx * H2 + half;
                const unsigned short* lbt = lb + tl * 2048 + lane * 8;
                bf16x8 bfr[4];
                #pragma unroll
                for (int nb = 0; nb < 4; ++nb)
                    bfr[nb] = *(const bf16x8*)(lbt + nb * 512);
                #pragma unroll
                for (int f = 0; f < 4; ++f) {
                    const unsigned short* ap =
                        inrow + (size_t)ix[f] * CIN + half * 32 + quad * 8;
                    uint4 av = v[f] ? *(const uint4*)ap : make_uint4(0u, 0u, 0u, 0u);
                    bf16x8 a = __builtin_bit_cast(bf16x8, av);
                    #pragma unroll
                    for (int nb = 0; nb < 4; ++nb)
                        acc[f][nb] = __builtin_amdgcn_mfma_f32_16x16x32_bf16(
                            a, bfr[nb], acc[f][nb], 0, 0, 0);
                }
            }
        }
    }

    // epilogue: C/D layout col = lane&15 (cout in nb), row = quad*4+reg (pixel in frag)
    int n0 = m;
    float bv[4];
    #pragma unroll
    for (int nb = 0; nb < 4; ++nb) bv[nb] = bias[nb * 16 + n0];
    #pragma unroll
    for (int f = 0; f < 4; ++f) {
        #pragma unroll
        for (int reg = 0; reg < 4; ++reg) {
            int i = f * 16 + quad * 4 + reg;
            int pm;
            if constexpr (MODE == CONV) pm = px_base + i;
            else pm = px_base + 2 * i + par;
            if (pm >= OUT_W) continue;
            size_t pix = (size_t)(b * OUT_H + y) * OUT_W + pm;
            float mk = 1.f;
            if constexpr (MASKED) mk = mask[pix];
            #pragma unroll
            for (int nb = 0; nb < 4; ++nb) {
                float o = fmaxf((acc[f][nb][reg] + bv[nb]) * mk, 0.f);
                if constexpr (OUT_F32)
                    ((float*)outv)[pix * 64 + nb * 16 + n0] = o;
                else
                    ((unsigned short*)outv)[pix * 64 + nb * 16 + n0] = f2bf(o);
            }
        }
    }
}

// ---------- host ----------
extern "C" void kernel_launch(void* const* d_in, const int* in_sizes, int n_in,
                              void* d_out, int out_size, void* d_ws, size_t ws_size,
                              hipStream_t stream) {
    const float* feat = (const float*)d_in[0];
    const int* coors  = (const int*)d_in[1];
    const float* w1 = (const float*)d_in[3];
    const float* b1 = (const float*)d_in[4];
    const float* w2 = (const float*)d_in[5];
    const float* b2 = (const float*)d_in[6];
    const float* w3 = (const float*)d_in[7];
    const float* b3 = (const float*)d_in[8];
    const float* wt = (const float*)d_in[9];
    const float* bt = (const float*)d_in[10];
    const float* w5 = (const float*)d_in[11];
    const float* b5 = (const float*)d_in[12];

    int N = in_sizes[0] / 32;  // 200000

    const size_t MB = 1024 * 1024;
    char* ws = (char*)d_ws;
    // layout (liveness-based reuse), total 177 MB:
    unsigned short* pk1 = (unsigned short*)(ws);             // 36,864 B
    unsigned short* pk2 = (unsigned short*)(ws + 36864);     // 73,728 B
    unsigned short* pk3 = (unsigned short*)(ws + 110592);
    unsigned short* pkt = (unsigned short*)(ws + 184320);
    unsigned short* pk5 = (unsigned short*)(ws + 258048);    // ends 331,776
    float* mask1 = (float*)(ws + 1 * MB);                    // 1 MB
    float* mask4 = (float*)(ws + 2 * MB);                    // 4.02 MB
    float* mask0 = (float*)(ws + 7 * MB);                    // 1 MB   (contiguous with x)
    float* x_f32 = (float*)(ws + 8 * MB);                    // 33.55 MB
    unsigned short* x_bf  = (unsigned short*)(ws + 42 * MB); // 16.78 MB
    unsigned short* h1    = (unsigned short*)(ws + 59 * MB); // 33.55 MB
    unsigned short* h2    = (unsigned short*)(ws + 93 * MB); // 33.55 MB
    unsigned short* h3    = (unsigned short*)(ws + 8 * MB);  // reuses x_f32 (dead after cast)
    unsigned short* h4    = (unsigned short*)(ws + 42 * MB); // 134.75 MB, reuses x_bf/h1/h2

    // 0: zero mask0 + x (contiguous 34,603,008 B)
    int nz4 = (262144 + 8388608) / 4;
    k_zero<<<(nz4 + 255) / 256, 256, 0, stream>>>(mask0, nz4);

    // 1: scatter (fp32 atomics)
    k_scatter<<<(N * 32 + 255) / 256, 256, 0, stream>>>(feat, coors, x_f32, mask0, N);

    // 2: masks + cast + weight packing
    k_mask1<<<(BATCH * HH * WW) / 256, 256, 0, stream>>>(mask0, mask1, BATCH * HH * WW);
    int m4tot = BATCH * HT * HT;
    k_mask4<<<(m4tot + 255) / 256, 256, 0, stream>>>(mask1, mask4, m4tot);
    k_cast<<<(1048576 + 255) / 256, 256, 0, stream>>>(x_f32, x_bf, 1048576);
    k_pack<<<9, 256, 0, stream>>>(w1, pk1, 9);
    k_pack<<<18, 256, 0, stream>>>(w2, pk2, 18);
    k_pack<<<18, 256, 0, stream>>>(w3, pk3, 18);
    k_pack<<<18, 256, 0, stream>>>(wt, pkt, 18);
    k_pack<<<18, 256, 0, stream>>>(w5, pk5, 18);

    // 3-5: conv stack at 256x256 (bf16 MFMA, 256 px/block)
    k_conv_mfma<32, 256, 256, 256, 256, 1, CONV, true, false>
        <<<BATCH * HH * 1, 256, 0, stream>>>(x_bf, pk1, b1, mask1, h1);
    k_conv_mfma<64, 256, 256, 256, 256, 1, CONV, true, false>
        <<<BATCH * HH * 1, 256, 0, stream>>>(h1, pk2, b2, mask1, h2);
    k_conv_mfma<64, 256, 256, 256, 256, 1, CONV, true, false>
        <<<BATCH * HH * 1, 256, 0, stream>>>(h2, pk3, b3, mask1, h3);

    // 6: transpose conv 256 -> 513 (parity-specialized waves)
    k_conv_mfma<64, 256, 256, HT, HT, 0, CONVT2, true, false>
        <<<BATCH * HT * 3, 256, 0, stream>>>(h3, pkt, bt, mask4, h4);

    // 7: final VALID conv 513 -> 511 into d_out (fp32)
    k_conv_mfma<64, HT, HT, HO, HO, 0, CONV, false, true>
        <<<BATCH * HO * 2, 256, 0, stream>>>(h4, pk5, b5, nullptr, (float*)d_out);
}